// Round 1
// baseline (350.065 us; speedup 1.0000x reference)
//
#include <hip/hip_runtime.h>
#include <math.h>

#define B_ 4096
#define F_ 24
#define C_ 32      // floats per emb row (128 B)

// One 64-lane wave per batch row.
//   lane = g*8 + m :  m = column-quad (owns columns 4m..4m+3 of the 32-float row),
//                     g = field group; the lane handles fields f = g + 8k, k=0..2.
// Round 1: each lane fetches its own 3 x/offset dwords (whole wave reads the
//   same two 96 B rows -> L1 broadcast; NO cross-lane traffic between rounds).
// Round 2: 3 float4 emb gathers (16 B/lane; one 64-lane load instruction covers
//   8 random 128 B rows, fully coalesced) + w_linear gathers on m==0 lanes,
//   all issued back-to-back before any waitcnt-dependent use.
// Power sums p1,p2,p3 kept as per-lane float4 over the lane's 3 fields, then
// xor-reduced across field groups (strides 8/16/32) -> every lane holds the
// complete per-column sums for its quad.
//   e2 = (p1^2 - p2)/2        on cols 0..15  (m < 4)
//   e3 = (p1^3 - 3p1p2 + 2p3)/6 on cols 16..31 (m >= 4)
// (Newton's identities; algebra validated in R1.)
__global__ __launch_bounds__(256) void fm_ho_kernel(
    const int*   __restrict__ x,
    const int*   __restrict__ offsets,
    const float* __restrict__ w_linear,
    const float* __restrict__ bias,
    const float* __restrict__ emb,
    float*       __restrict__ out)
{
    const int tid  = threadIdx.x;
    const int lane = tid & 63;
    const int wave = tid >> 6;
    const int b    = blockIdx.x * 4 + wave;

    const int m = lane & 7;    // column quad
    const int g = lane >> 3;   // field group

    const float bval = bias[0];   // uniform scalar load, issued early

    // ---- round 1: per-lane index computation (L1-broadcast rows) ----
    int rows[3];
    #pragma unroll
    for (int k = 0; k < 3; ++k) {
        const int f = g + 8 * k;
        rows[k] = x[b * F_ + f] + offsets[f];
    }

    // ---- round 2: all gathers issued before any use ----
    float4 v[3];
    #pragma unroll
    for (int k = 0; k < 3; ++k)
        v[k] = *reinterpret_cast<const float4*>(
                   emb + (size_t)rows[k] * C_ + m * 4);

    float wl = 0.f;
    if (m == 0) {                 // 8 lanes x 3 fields = 24 w-gathers, once each
        #pragma unroll
        for (int k = 0; k < 3; ++k)
            wl += w_linear[rows[k]];
    }

    // per-column power sums over this lane's 3 fields
    float q1[4] = {0.f, 0.f, 0.f, 0.f};
    float q2[4] = {0.f, 0.f, 0.f, 0.f};
    float q3[4] = {0.f, 0.f, 0.f, 0.f};
    #pragma unroll
    for (int k = 0; k < 3; ++k) {
        const float* pv = reinterpret_cast<const float*>(&v[k]);
        #pragma unroll
        for (int i = 0; i < 4; ++i) {
            const float t = pv[i];
            q1[i] += t;
            q2[i] += t * t;
            q3[i] += t * t * t;
        }
    }

    // combine the 8 field groups: xor over lane strides 8,16,32
    #pragma unroll
    for (int d = 8; d <= 32; d <<= 1) {
        #pragma unroll
        for (int i = 0; i < 4; ++i) {
            q1[i] += __shfl_xor(q1[i], d, 64);
            q2[i] += __shfl_xor(q2[i], d, 64);
            q3[i] += __shfl_xor(q3[i], d, 64);
        }
    }

    // per-quad nonlinear terms (complete power sums now in every lane)
    float term = 0.f;
    if (m < 4) {
        #pragma unroll
        for (int i = 0; i < 4; ++i)
            term += q1[i] * q1[i] - q2[i];
        term *= 0.5f;
    } else {
        #pragma unroll
        for (int i = 0; i < 4; ++i)
            term += q1[i] * q1[i] * q1[i] - 3.f * q1[i] * q2[i] + 2.f * q3[i];
        term *= (1.0f / 6.0f);
    }

    // count each contribution exactly once in the 64-lane reduction:
    // term only on the g==0 octet (8 quads), wl only on m==0 lanes.
    float contrib = wl + ((g == 0) ? term : 0.f);
    #pragma unroll
    for (int off = 32; off > 0; off >>= 1)
        contrib += __shfl_xor(contrib, off, 64);

    if (lane == 0)
        out[b] = 1.0f / (1.0f + __expf(-(contrib + bval)));
}

extern "C" void kernel_launch(void* const* d_in, const int* in_sizes, int n_in,
                              void* d_out, int out_size, void* d_ws, size_t ws_size,
                              hipStream_t stream) {
    const int*   x       = (const int*)  d_in[0];
    const int*   offsets = (const int*)  d_in[1];
    const float* w       = (const float*)d_in[2];
    const float* bias    = (const float*)d_in[3];
    const float* emb     = (const float*)d_in[4];
    float*       out     = (float*)      d_out;

    // 1 wave per row, 4 waves per block -> 1024 blocks, 4096 waves (16/CU)
    fm_ho_kernel<<<B_ / 4, 256, 0, stream>>>(x, offsets, w, bias, emb, out);
}